// Round 1
// baseline (440.554 us; speedup 1.0000x reference)
//
#include <hip/hip_runtime.h>
#include <hip/hip_bf16.h>

// SelfAttentionMasked: B=4, N=2048, DIM=1024, H=16, DH=64
// Pipeline: cvt(x) -> transpose_cvt(Wqkv, Wout) -> QKV GEMM (bf16 MFMA)
//           -> flash attention (bf16 MFMA, f32 softmax) -> out GEMM + bias (f32 out)

typedef __attribute__((ext_vector_type(8))) short bf16x8;
typedef __attribute__((ext_vector_type(4))) float f32x4;

__device__ __forceinline__ unsigned short f2bf(float f) {
  unsigned u = __builtin_bit_cast(unsigned, f);
  u += 0x7fffu + ((u >> 16) & 1u);   // RNE
  return (unsigned short)(u >> 16);
}

// ---------------- convert f32 -> bf16 flat ----------------
__global__ __launch_bounds__(256) void k_cvt(const float* __restrict__ in,
                                             unsigned short* __restrict__ out) {
  int i = (blockIdx.x * 256 + threadIdx.x) * 4;
  float4 v = *reinterpret_cast<const float4*>(in + i);
  ushort4 o;
  o.x = f2bf(v.x); o.y = f2bf(v.y); o.z = f2bf(v.z); o.w = f2bf(v.w);
  *reinterpret_cast<ushort4*>(out + i) = o;
}

// ------- transpose + convert: in [rows][cols] f32 -> out [cols][rows] bf16 -------
__global__ __launch_bounds__(256) void k_transpose_cvt(const float* __restrict__ in,
                                                       unsigned short* __restrict__ out,
                                                       int rows, int cols) {
  __shared__ float tile[32][33];
  int tx = threadIdx.x & 31, ty = threadIdx.x >> 5;  // 32 x 8
  int c0 = blockIdx.x * 32, r0 = blockIdx.y * 32;
#pragma unroll
  for (int i = 0; i < 32; i += 8)
    tile[ty + i][tx] = in[(size_t)(r0 + ty + i) * cols + (c0 + tx)];
  __syncthreads();
#pragma unroll
  for (int i = 0; i < 32; i += 8)
    out[(size_t)(c0 + ty + i) * rows + (r0 + tx)] = f2bf(tile[tx][ty + i]);
}

// ---------------- GEMM: C[8192][N] = A[8192][1024] @ Bt[N][1024]^T ----------------
// EPI==0: scatter bf16 into Q/K/V head layouts [b*16+h][2048][64]
// EPI==1: f32 out + bias
template <int EPI>
__global__ __launch_bounds__(256) void k_gemm(
    const unsigned short* __restrict__ A, const unsigned short* __restrict__ Bt,
    unsigned short* __restrict__ Qo, unsigned short* __restrict__ Ko,
    unsigned short* __restrict__ Vo, float* __restrict__ Co,
    const float* __restrict__ bias, int N) {
  __shared__ __align__(16) short As[128][72];  // stride 72 elem = 144 B (16B aligned, ~2-way banks)
  __shared__ __align__(16) short Bs[128][72];
  const int t = threadIdx.x;
  const int bn = blockIdx.x, bm = blockIdx.y;
  const int wid = t >> 6, lane = t & 63, g = lane >> 4, l15 = lane & 15;
  const int wr = wid >> 1, wc = wid & 1;
  f32x4 zero = {0.f, 0.f, 0.f, 0.f};
  f32x4 acc[4][4];
#pragma unroll
  for (int i = 0; i < 4; ++i)
#pragma unroll
    for (int j = 0; j < 4; ++j) acc[i][j] = zero;

  const size_t abase = (size_t)bm * 128 * 1024;
  const size_t bbase = (size_t)bn * 128 * 1024;

  for (int k0 = 0; k0 < 1024; k0 += 64) {
#pragma unroll
    for (int q = 0; q < 4; ++q) {
      int idx = t + q * 256;          // 1024 chunks of 8 bf16
      int r = idx >> 3, c = (idx & 7) * 8;
      *reinterpret_cast<bf16x8*>(&As[r][c]) =
          *reinterpret_cast<const bf16x8*>(&A[abase + (size_t)r * 1024 + k0 + c]);
      *reinterpret_cast<bf16x8*>(&Bs[r][c]) =
          *reinterpret_cast<const bf16x8*>(&Bt[bbase + (size_t)r * 1024 + k0 + c]);
    }
    __syncthreads();
#pragma unroll
    for (int ks = 0; ks < 2; ++ks) {
      bf16x8 a[4], b[4];
#pragma unroll
      for (int mi = 0; mi < 4; ++mi)
        a[mi] = *reinterpret_cast<const bf16x8*>(&As[wr * 64 + mi * 16 + l15][ks * 32 + g * 8]);
#pragma unroll
      for (int ni = 0; ni < 4; ++ni)
        b[ni] = *reinterpret_cast<const bf16x8*>(&Bs[wc * 64 + ni * 16 + l15][ks * 32 + g * 8]);
#pragma unroll
      for (int mi = 0; mi < 4; ++mi)
#pragma unroll
        for (int ni = 0; ni < 4; ++ni)
          acc[mi][ni] = __builtin_amdgcn_mfma_f32_16x16x32_bf16(a[mi], b[ni], acc[mi][ni], 0, 0, 0);
    }
    __syncthreads();
  }

#pragma unroll
  for (int mi = 0; mi < 4; ++mi) {
#pragma unroll
    for (int ni = 0; ni < 4; ++ni) {
#pragma unroll
      for (int j = 0; j < 4; ++j) {
        float v = acc[mi][ni][j];
        int row = bm * 128 + wr * 64 + mi * 16 + g * 4 + j;  // D row map
        int col = bn * 128 + wc * 64 + ni * 16 + l15;        // D col map
        if (EPI == 0) {
          int b = row >> 11, nn = row & 2047;
          int s = col >> 10, rem = col & 1023;
          int h = rem >> 6, d = rem & 63;
          size_t off = (((size_t)(b * 16 + h)) * 2048 + nn) * 64 + d;
          unsigned short bv = f2bf(v);
          if (s == 0) Qo[off] = bv;
          else if (s == 1) Ko[off] = bv;
          else Vo[off] = bv;
        } else {
          Co[(size_t)row * 1024 + col] = v + bias[col];
        }
      }
    }
  }
}

// ---------------- flash attention ----------------
// grid: (b*16+h)*32 + qt, 2048 blocks, 256 threads = 4 waves x 16 q-rows
__global__ __launch_bounds__(256) void k_attn(
    const unsigned short* __restrict__ Q, const unsigned short* __restrict__ K,
    const unsigned short* __restrict__ V, const int* __restrict__ mask,
    unsigned short* __restrict__ O) {
  __shared__ __align__(16) short Qs[64][72];
  __shared__ __align__(16) short Ks[64][72];
  __shared__ __align__(16) short Vt[64][72];      // V transposed: [d][key]
  __shared__ __align__(16) short Ps[4][16][72];   // per-wave P tile [q][key]
  const int bid = blockIdx.x;
  const int qt = bid & 31, bh = bid >> 5;
  const int b = bh >> 4, h = bh & 15;
  const int t = threadIdx.x, wid = t >> 6, lane = t & 63, g = lane >> 4, l15 = lane & 15;
  const unsigned short* Qb = Q + (size_t)bh * (2048 * 64);
  const unsigned short* Kb = K + (size_t)bh * (2048 * 64);
  const unsigned short* Vb = V + (size_t)bh * (2048 * 64);

#pragma unroll
  for (int q = 0; q < 2; ++q) {  // Q tile: 512 chunks of 8
    int idx = t + q * 256;
    int r = idx >> 3, c = (idx & 7) * 8;
    *reinterpret_cast<bf16x8*>(&Qs[r][c]) =
        *reinterpret_cast<const bf16x8*>(&Qb[((size_t)(qt * 64 + r)) * 64 + c]);
  }

  f32x4 zero = {0.f, 0.f, 0.f, 0.f};
  f32x4 oacc[4];
#pragma unroll
  for (int nf = 0; nf < 4; ++nf) oacc[nf] = zero;
  float mj[4] = {-1e30f, -1e30f, -1e30f, -1e30f};
  float lj[4] = {0.f, 0.f, 0.f, 0.f};

  for (int kt = 0; kt < 32; ++kt) {
    // stage K tile and V^T tile
#pragma unroll
    for (int q = 0; q < 2; ++q) {
      int idx = t + q * 256;
      int r = idx >> 3, c = (idx & 7) * 8;
      *reinterpret_cast<bf16x8*>(&Ks[r][c]) =
          *reinterpret_cast<const bf16x8*>(&Kb[((size_t)(kt * 64 + r)) * 64 + c]);
      bf16x8 vv = *reinterpret_cast<const bf16x8*>(&Vb[((size_t)(kt * 64 + r)) * 64 + c]);
#pragma unroll
      for (int i = 0; i < 8; ++i) Vt[c + i][r] = vv[i];
    }
    __syncthreads();

    // S = Q @ K^T  (D: row=q local, col=key local)
    f32x4 sf[4];
#pragma unroll
    for (int nf = 0; nf < 4; ++nf) sf[nf] = zero;
#pragma unroll
    for (int ks = 0; ks < 2; ++ks) {
      bf16x8 aq = *reinterpret_cast<const bf16x8*>(&Qs[wid * 16 + l15][ks * 32 + g * 8]);
#pragma unroll
      for (int nf = 0; nf < 4; ++nf) {
        bf16x8 bk = *reinterpret_cast<const bf16x8*>(&Ks[nf * 16 + l15][ks * 32 + g * 8]);
        sf[nf] = __builtin_amdgcn_mfma_f32_16x16x32_bf16(aq, bk, sf[nf], 0, 0, 0);
      }
    }

    // mask + online softmax, per q-row j
    const int kbase = kt * 64;
#pragma unroll
    for (int j = 0; j < 4; ++j) {
      int qg = qt * 64 + wid * 16 + g * 4 + j;
      const int* mrow = mask + ((size_t)b * 2048 + qg) * 2048 + kbase;
      float pv[4];
      float mx = -1e30f;
#pragma unroll
      for (int nf = 0; nf < 4; ++nf) {
        float sv = sf[nf][j] * 0.125f;
        sv = (mrow[nf * 16 + l15] == 1) ? -1e30f : sv;
        pv[nf] = sv;
        mx = fmaxf(mx, sv);
      }
      mx = fmaxf(mx, __shfl_xor(mx, 1));
      mx = fmaxf(mx, __shfl_xor(mx, 2));
      mx = fmaxf(mx, __shfl_xor(mx, 4));
      mx = fmaxf(mx, __shfl_xor(mx, 8));
      float mn = fmaxf(mj[j], mx);
      float scale = __expf(mj[j] - mn);
      float ls = 0.f;
#pragma unroll
      for (int nf = 0; nf < 4; ++nf) {
        float e = __expf(pv[nf] - mn);
        pv[nf] = e;
        ls += e;
      }
      ls += __shfl_xor(ls, 1);
      ls += __shfl_xor(ls, 2);
      ls += __shfl_xor(ls, 4);
      ls += __shfl_xor(ls, 8);
      lj[j] = lj[j] * scale + ls;
      mj[j] = mn;
#pragma unroll
      for (int nf = 0; nf < 4; ++nf) {
        oacc[nf][j] *= scale;
        Ps[wid][g * 4 + j][nf * 16 + l15] = (short)f2bf(pv[nf]);
      }
    }
    // within-wave LDS write->read ordering (ds ops ordered by memory clobber; drain)
    asm volatile("s_waitcnt lgkmcnt(0)" ::: "memory");
    __builtin_amdgcn_sched_barrier(0);

    // O += P @ V   (A = Ps rows, B = Vt rows contiguous)
#pragma unroll
    for (int ks = 0; ks < 2; ++ks) {
      bf16x8 ap = *reinterpret_cast<const bf16x8*>(&Ps[wid][l15][ks * 32 + g * 8]);
#pragma unroll
      for (int nf = 0; nf < 4; ++nf) {
        bf16x8 bv = *reinterpret_cast<const bf16x8*>(&Vt[nf * 16 + l15][ks * 32 + g * 8]);
        oacc[nf] = __builtin_amdgcn_mfma_f32_16x16x32_bf16(ap, bv, oacc[nf], 0, 0, 0);
      }
    }
    __syncthreads();
  }

  // write attention output: ATT[b][n][h*64+d] bf16
#pragma unroll
  for (int nf = 0; nf < 4; ++nf) {
#pragma unroll
    for (int j = 0; j < 4; ++j) {
      float v = oacc[nf][j] / lj[j];
      int qg = qt * 64 + wid * 16 + g * 4 + j;
      int d = nf * 16 + l15;
      O[((size_t)b * 2048 + qg) * 1024 + h * 64 + d] = f2bf(v);
    }
  }
}

extern "C" void kernel_launch(void* const* d_in, const int* in_sizes, int n_in,
                              void* d_out, int out_size, void* d_ws, size_t ws_size,
                              hipStream_t stream) {
  (void)in_sizes; (void)n_in; (void)out_size; (void)ws_size;
  const float* x = (const float*)d_in[0];
  const int* mask = (const int*)d_in[1];
  const float* Wqkv = (const float*)d_in[2];
  const float* Wout = (const float*)d_in[3];
  const float* bout = (const float*)d_in[4];
  float* out = (float*)d_out;

  unsigned short* ws = (unsigned short*)d_ws;
  unsigned short* Xb   = ws;                  // 8,388,608 elems
  unsigned short* Wq_t = Xb + 8388608;        // 3,145,728
  unsigned short* Wo_t = Wq_t + 3145728;      // 1,048,576
  unsigned short* Qa   = Wo_t + 1048576;      // 8,388,608
  unsigned short* Ka   = Qa + 8388608;        // 8,388,608
  unsigned short* Va   = Ka + 8388608;        // 8,388,608
  unsigned short* ATT  = Va + 8388608;        // 8,388,608  (total ~92.3 MB)

  k_cvt<<<8192, 256, 0, stream>>>(x, Xb);
  k_transpose_cvt<<<dim3(96, 32), 256, 0, stream>>>(Wqkv, Wq_t, 1024, 3072);
  k_transpose_cvt<<<dim3(32, 32), 256, 0, stream>>>(Wout, Wo_t, 1024, 1024);
  k_gemm<0><<<dim3(24, 64), 256, 0, stream>>>(Xb, Wq_t, Qa, Ka, Va, nullptr, nullptr, 3072);
  k_attn<<<2048, 256, 0, stream>>>(Qa, Ka, Va, mask, ATT);
  k_gemm<1><<<dim3(8, 64), 256, 0, stream>>>(ATT, Wo_t, nullptr, nullptr, nullptr, out, bout, 1024);
}

// Round 2
// 391.955 us; speedup vs baseline: 1.1240x; 1.1240x over previous
//
#include <hip/hip_runtime.h>
#include <hip/hip_bf16.h>

// SelfAttentionMasked: B=4, N=2048, DIM=1024, H=16, DH=64
// Pipeline: cvt(x) -> transpose_cvt(Wqkv, Wout) -> packmask -> QKV GEMM (bf16 MFMA,
//           V stored transposed) -> flash attention (bf16 MFMA, bitmask, f32 softmax)
//           -> out GEMM + bias (f32 out)

typedef __attribute__((ext_vector_type(8))) short bf16x8;
typedef __attribute__((ext_vector_type(4))) float f32x4;

__device__ __forceinline__ unsigned short f2bf(float f) {
  unsigned u = __builtin_bit_cast(unsigned, f);
  u += 0x7fffu + ((u >> 16) & 1u);   // RNE
  return (unsigned short)(u >> 16);
}

// ---------------- convert f32 -> bf16 flat ----------------
__global__ __launch_bounds__(256) void k_cvt(const float* __restrict__ in,
                                             unsigned short* __restrict__ out) {
  int i = (blockIdx.x * 256 + threadIdx.x) * 4;
  float4 v = *reinterpret_cast<const float4*>(in + i);
  ushort4 o;
  o.x = f2bf(v.x); o.y = f2bf(v.y); o.z = f2bf(v.z); o.w = f2bf(v.w);
  *reinterpret_cast<ushort4*>(out + i) = o;
}

// ------- transpose + convert: in [rows][cols] f32 -> out [cols][rows] bf16 -------
__global__ __launch_bounds__(256) void k_transpose_cvt(const float* __restrict__ in,
                                                       unsigned short* __restrict__ out,
                                                       int rows, int cols) {
  __shared__ float tile[32][33];
  int tx = threadIdx.x & 31, ty = threadIdx.x >> 5;  // 32 x 8
  int c0 = blockIdx.x * 32, r0 = blockIdx.y * 32;
#pragma unroll
  for (int i = 0; i < 32; i += 8)
    tile[ty + i][tx] = in[(size_t)(r0 + ty + i) * cols + (c0 + tx)];
  __syncthreads();
#pragma unroll
  for (int i = 0; i < 32; i += 8)
    out[(size_t)(c0 + ty + i) * rows + (r0 + tx)] = f2bf(tile[tx][ty + i]);
}

// ------- pack mask int32 [row][2048] -> bits uint64 [row][32] (bit k = masked) ----
__global__ __launch_bounds__(256) void k_packmask(const int* __restrict__ mask,
                                                  unsigned long long* __restrict__ pack) {
  const int row = blockIdx.x;              // b*2048 + n
  const int t = threadIdx.x, w = t >> 6, lane = t & 63;
  const int* mrow = mask + (size_t)row * 2048;
#pragma unroll
  for (int it = 0; it < 8; ++it) {
    int key = it * 256 + w * 64 + lane;
    unsigned long long bal = __ballot(mrow[key] == 1);
    if (lane == 0) pack[(size_t)row * 32 + it * 4 + w] = bal;
  }
}

// ---------------- GEMM: C[8192][N] = A[8192][1024] @ Bt[N][1024]^T ----------------
// EPI==0: scatter bf16 into Q/K [bh][2048][64] and V TRANSPOSED [bh][64][2048]
// EPI==1: f32 out + bias
template <int EPI>
__global__ __launch_bounds__(256) void k_gemm(
    const unsigned short* __restrict__ A, const unsigned short* __restrict__ Bt,
    unsigned short* __restrict__ Qo, unsigned short* __restrict__ Ko,
    unsigned short* __restrict__ Vo, float* __restrict__ Co,
    const float* __restrict__ bias, int N) {
  __shared__ __align__(16) short As[128][72];  // stride 72 elem = 144 B
  __shared__ __align__(16) short Bs[128][72];
  const int t = threadIdx.x;
  const int bn = blockIdx.x, bm = blockIdx.y;
  const int wid = t >> 6, lane = t & 63, g = lane >> 4, l15 = lane & 15;
  const int wr = wid >> 1, wc = wid & 1;
  f32x4 zero = {0.f, 0.f, 0.f, 0.f};
  f32x4 acc[4][4];
#pragma unroll
  for (int i = 0; i < 4; ++i)
#pragma unroll
    for (int j = 0; j < 4; ++j) acc[i][j] = zero;

  const size_t abase = (size_t)bm * 128 * 1024;
  const size_t bbase = (size_t)bn * 128 * 1024;

  for (int k0 = 0; k0 < 1024; k0 += 64) {
#pragma unroll
    for (int q = 0; q < 4; ++q) {
      int idx = t + q * 256;          // 1024 chunks of 8 bf16
      int r = idx >> 3, c = (idx & 7) * 8;
      *reinterpret_cast<bf16x8*>(&As[r][c]) =
          *reinterpret_cast<const bf16x8*>(&A[abase + (size_t)r * 1024 + k0 + c]);
      *reinterpret_cast<bf16x8*>(&Bs[r][c]) =
          *reinterpret_cast<const bf16x8*>(&Bt[bbase + (size_t)r * 1024 + k0 + c]);
    }
    __syncthreads();
#pragma unroll
    for (int ks = 0; ks < 2; ++ks) {
      bf16x8 a[4], b[4];
#pragma unroll
      for (int mi = 0; mi < 4; ++mi)
        a[mi] = *reinterpret_cast<const bf16x8*>(&As[wr * 64 + mi * 16 + l15][ks * 32 + g * 8]);
#pragma unroll
      for (int ni = 0; ni < 4; ++ni)
        b[ni] = *reinterpret_cast<const bf16x8*>(&Bs[wc * 64 + ni * 16 + l15][ks * 32 + g * 8]);
#pragma unroll
      for (int mi = 0; mi < 4; ++mi)
#pragma unroll
        for (int ni = 0; ni < 4; ++ni)
          acc[mi][ni] = __builtin_amdgcn_mfma_f32_16x16x32_bf16(a[mi], b[ni], acc[mi][ni], 0, 0, 0);
    }
    __syncthreads();
  }

#pragma unroll
  for (int mi = 0; mi < 4; ++mi) {
#pragma unroll
    for (int ni = 0; ni < 4; ++ni) {
#pragma unroll
      for (int j = 0; j < 4; ++j) {
        float v = acc[mi][ni][j];
        int row = bm * 128 + wr * 64 + mi * 16 + g * 4 + j;  // D row map
        int col = bn * 128 + wc * 64 + ni * 16 + l15;        // D col map
        if (EPI == 0) {
          int b = row >> 11, nn = row & 2047;
          int s = col >> 10, rem = col & 1023;
          int h = rem >> 6, d = rem & 63;
          int bh = b * 16 + h;
          unsigned short bv = f2bf(v);
          if (s == 0) Qo[(((size_t)bh) * 2048 + nn) * 64 + d] = bv;
          else if (s == 1) Ko[(((size_t)bh) * 2048 + nn) * 64 + d] = bv;
          else Vo[(((size_t)bh) * 64 + d) * 2048 + nn] = bv;   // V transposed
        } else {
          Co[(size_t)row * 1024 + col] = v + bias[col];
        }
      }
    }
  }
}

// ---------------- flash attention ----------------
// grid: (b*16+h)*32 + qt, 2048 blocks, 256 threads = 4 waves x 16 q-rows
__global__ __launch_bounds__(256) void k_attn(
    const unsigned short* __restrict__ Q, const unsigned short* __restrict__ K,
    const unsigned short* __restrict__ Vt_g, const unsigned long long* __restrict__ pack,
    unsigned short* __restrict__ O) {
  __shared__ __align__(16) short Qs[64][72];
  __shared__ __align__(16) short Ks[64][72];
  __shared__ __align__(16) short Vt[64][72];      // V^T tile: [d][key]
  __shared__ __align__(16) short Ps[4][16][72];   // per-wave P tile [q][key]
  const int bid = blockIdx.x;
  const int qt = bid & 31, bh = bid >> 5;
  const int b = bh >> 4;
  const int t = threadIdx.x, wid = t >> 6, lane = t & 63, g = lane >> 4, l15 = lane & 15;
  const unsigned short* Qb = Q + (size_t)bh * (2048 * 64);
  const unsigned short* Kb = K + (size_t)bh * (2048 * 64);
  const unsigned short* Vb = Vt_g + (size_t)bh * (64 * 2048);

#pragma unroll
  for (int q = 0; q < 2; ++q) {  // Q tile: 512 chunks of 8
    int idx = t + q * 256;
    int r = idx >> 3, c = (idx & 7) * 8;
    *reinterpret_cast<bf16x8*>(&Qs[r][c]) =
        *reinterpret_cast<const bf16x8*>(&Qb[((size_t)(qt * 64 + r)) * 64 + c]);
  }

  f32x4 zero = {0.f, 0.f, 0.f, 0.f};
  f32x4 oacc[4];
#pragma unroll
  for (int nf = 0; nf < 4; ++nf) oacc[nf] = zero;
  float mj[4] = {-1e30f, -1e30f, -1e30f, -1e30f};
  float lj[4] = {0.f, 0.f, 0.f, 0.f};

  for (int kt = 0; kt < 32; ++kt) {
    // stage K tile [key][d] and V^T tile [d][key] -- both linear bf16x8 copies
#pragma unroll
    for (int q = 0; q < 2; ++q) {
      int idx = t + q * 256;
      int r = idx >> 3, c = (idx & 7) * 8;
      *reinterpret_cast<bf16x8*>(&Ks[r][c]) =
          *reinterpret_cast<const bf16x8*>(&Kb[((size_t)(kt * 64 + r)) * 64 + c]);
      *reinterpret_cast<bf16x8*>(&Vt[r][c]) =
          *reinterpret_cast<const bf16x8*>(&Vb[(size_t)r * 2048 + kt * 64 + c]);
    }
    __syncthreads();

    // S = Q @ K^T  (D: row=q local, col=key local)
    f32x4 sf[4];
#pragma unroll
    for (int nf = 0; nf < 4; ++nf) sf[nf] = zero;
#pragma unroll
    for (int ks = 0; ks < 2; ++ks) {
      bf16x8 aq = *reinterpret_cast<const bf16x8*>(&Qs[wid * 16 + l15][ks * 32 + g * 8]);
#pragma unroll
      for (int nf = 0; nf < 4; ++nf) {
        bf16x8 bk = *reinterpret_cast<const bf16x8*>(&Ks[nf * 16 + l15][ks * 32 + g * 8]);
        sf[nf] = __builtin_amdgcn_mfma_f32_16x16x32_bf16(aq, bk, sf[nf], 0, 0, 0);
      }
    }

    // mask (bit-packed) + online softmax, per q-row j
#pragma unroll
    for (int j = 0; j < 4; ++j) {
      int qg = qt * 64 + wid * 16 + g * 4 + j;
      unsigned long long mw = pack[((size_t)b * 2048 + qg) * 32 + kt];
      float pv[4];
      float mx = -1e30f;
#pragma unroll
      for (int nf = 0; nf < 4; ++nf) {
        unsigned chunk = (unsigned)(mw >> (nf * 16)) & 0xFFFFu;  // nf is compile-time
        float sv = sf[nf][j] * 0.125f;
        sv = ((chunk >> l15) & 1u) ? -1e30f : sv;
        pv[nf] = sv;
        mx = fmaxf(mx, sv);
      }
      mx = fmaxf(mx, __shfl_xor(mx, 1));
      mx = fmaxf(mx, __shfl_xor(mx, 2));
      mx = fmaxf(mx, __shfl_xor(mx, 4));
      mx = fmaxf(mx, __shfl_xor(mx, 8));
      float mn = fmaxf(mj[j], mx);
      float scale = __expf(mj[j] - mn);
      float ls = 0.f;
#pragma unroll
      for (int nf = 0; nf < 4; ++nf) {
        float e = __expf(pv[nf] - mn);
        pv[nf] = e;
        ls += e;
      }
      ls += __shfl_xor(ls, 1);
      ls += __shfl_xor(ls, 2);
      ls += __shfl_xor(ls, 4);
      ls += __shfl_xor(ls, 8);
      lj[j] = lj[j] * scale + ls;
      mj[j] = mn;
#pragma unroll
      for (int nf = 0; nf < 4; ++nf) {
        oacc[nf][j] *= scale;
        Ps[wid][g * 4 + j][nf * 16 + l15] = (short)f2bf(pv[nf]);
      }
    }
    // within-wave LDS write->read ordering (ds ops ordered by memory clobber; drain)
    asm volatile("s_waitcnt lgkmcnt(0)" ::: "memory");
    __builtin_amdgcn_sched_barrier(0);

    // O += P @ V   (A = Ps rows, B = Vt rows contiguous)
#pragma unroll
    for (int ks = 0; ks < 2; ++ks) {
      bf16x8 ap = *reinterpret_cast<const bf16x8*>(&Ps[wid][l15][ks * 32 + g * 8]);
#pragma unroll
      for (int nf = 0; nf < 4; ++nf) {
        bf16x8 bv = *reinterpret_cast<const bf16x8*>(&Vt[nf * 16 + l15][ks * 32 + g * 8]);
        oacc[nf] = __builtin_amdgcn_mfma_f32_16x16x32_bf16(ap, bv, oacc[nf], 0, 0, 0);
      }
    }
    __syncthreads();
  }

  // write attention output: ATT[b][n][h*64+d] bf16
  const int h = bh & 15;
#pragma unroll
  for (int nf = 0; nf < 4; ++nf) {
#pragma unroll
    for (int j = 0; j < 4; ++j) {
      float v = oacc[nf][j] / lj[j];
      int qg = qt * 64 + wid * 16 + g * 4 + j;
      int d = nf * 16 + l15;
      O[((size_t)b * 2048 + qg) * 1024 + h * 64 + d] = f2bf(v);
    }
  }
}

extern "C" void kernel_launch(void* const* d_in, const int* in_sizes, int n_in,
                              void* d_out, int out_size, void* d_ws, size_t ws_size,
                              hipStream_t stream) {
  (void)in_sizes; (void)n_in; (void)out_size; (void)ws_size;
  const float* x = (const float*)d_in[0];
  const int* mask = (const int*)d_in[1];
  const float* Wqkv = (const float*)d_in[2];
  const float* Wout = (const float*)d_in[3];
  const float* bout = (const float*)d_in[4];
  float* out = (float*)d_out;

  unsigned short* ws = (unsigned short*)d_ws;
  unsigned short* Xb   = ws;                  // 8,388,608 elems
  unsigned short* Wq_t = Xb + 8388608;        // 3,145,728
  unsigned short* Wo_t = Wq_t + 3145728;      // 1,048,576
  unsigned short* Qa   = Wo_t + 1048576;      // 8,388,608
  unsigned short* Ka   = Qa + 8388608;        // 8,388,608
  unsigned short* Va   = Ka + 8388608;        // 8,388,608 (transposed [bh][64][2048])
  unsigned short* ATT  = Va + 8388608;        // 8,388,608
  unsigned long long* MP = (unsigned long long*)(ATT + 8388608);  // 4*2048*32 u64 = 2 MB

  k_cvt<<<8192, 256, 0, stream>>>(x, Xb);
  k_transpose_cvt<<<dim3(96, 32), 256, 0, stream>>>(Wqkv, Wq_t, 1024, 3072);
  k_transpose_cvt<<<dim3(32, 32), 256, 0, stream>>>(Wout, Wo_t, 1024, 1024);
  k_packmask<<<8192, 256, 0, stream>>>(mask, MP);
  k_gemm<0><<<dim3(24, 64), 256, 0, stream>>>(Xb, Wq_t, Qa, Ka, Va, nullptr, nullptr, 3072);
  k_attn<<<2048, 256, 0, stream>>>(Qa, Ka, Va, MP, ATT);
  k_gemm<1><<<dim3(8, 64), 256, 0, stream>>>(ATT, Wo_t, nullptr, nullptr, nullptr, out, bout, 1024);
}

// Round 3
// 297.806 us; speedup vs baseline: 1.4793x; 1.3161x over previous
//
#include <hip/hip_runtime.h>
#include <hip/hip_bf16.h>

// SelfAttentionMasked: B=4, N=2048, DIM=1024, H=16, DH=64
// cvt(x) -> transpose_cvt(W) -> packmask -> QKV GEMM (gload_lds+swizzle, Q pre-scaled)
// -> flash attn (no-max softmax, bitmask, dbuf gload_lds) -> out GEMM + bias

typedef __attribute__((ext_vector_type(8))) short bf16x8;
typedef __attribute__((ext_vector_type(4))) float f32x4;

__device__ __forceinline__ unsigned short f2bf(float f) {
  unsigned u = __builtin_bit_cast(unsigned, f);
  u += 0x7fffu + ((u >> 16) & 1u);   // RNE
  return (unsigned short)(u >> 16);
}

// async global->LDS, 16B per lane; LDS dest must be linear (base + lane*16)
__device__ __forceinline__ void gload16(const void* g, void* l) {
  __builtin_amdgcn_global_load_lds(
      (const __attribute__((address_space(1))) unsigned int*)g,
      (__attribute__((address_space(3))) unsigned int*)l, 16, 0, 0);
}

// swizzled b128 read from a [rows][64-elem] linear LDS tile staged with
// source-byte ^= ((row&7)<<4). elem must be a multiple of 8.
__device__ __forceinline__ bf16x8 ldsw(const short* base, int row, int elem) {
  const char* p = (const char*)base + row * 128 + ((elem * 2) ^ ((row & 7) << 4));
  return *(const bf16x8*)p;
}

// ---------------- convert f32 -> bf16 flat ----------------
__global__ __launch_bounds__(256) void k_cvt(const float* __restrict__ in,
                                             unsigned short* __restrict__ out) {
  int i = (blockIdx.x * 256 + threadIdx.x) * 4;
  float4 v = *reinterpret_cast<const float4*>(in + i);
  ushort4 o;
  o.x = f2bf(v.x); o.y = f2bf(v.y); o.z = f2bf(v.z); o.w = f2bf(v.w);
  *reinterpret_cast<ushort4*>(out + i) = o;
}

// ------- transpose + convert: in [rows][cols] f32 -> out [cols][rows] bf16 -------
__global__ __launch_bounds__(256) void k_transpose_cvt(const float* __restrict__ in,
                                                       unsigned short* __restrict__ out,
                                                       int rows, int cols) {
  __shared__ float tile[32][33];
  int tx = threadIdx.x & 31, ty = threadIdx.x >> 5;  // 32 x 8
  int c0 = blockIdx.x * 32, r0 = blockIdx.y * 32;
#pragma unroll
  for (int i = 0; i < 32; i += 8)
    tile[ty + i][tx] = in[(size_t)(r0 + ty + i) * cols + (c0 + tx)];
  __syncthreads();
#pragma unroll
  for (int i = 0; i < 32; i += 8)
    out[(size_t)(c0 + ty + i) * rows + (r0 + tx)] = f2bf(tile[tx][ty + i]);
}

// ------- pack mask int32 [row][2048] -> bits uint64 [row][32] (bit k = masked) ----
__global__ __launch_bounds__(256) void k_packmask(const int* __restrict__ mask,
                                                  unsigned long long* __restrict__ pack) {
  const int row = blockIdx.x;              // b*2048 + n
  const int t = threadIdx.x, w = t >> 6, lane = t & 63;
  const int* mrow = mask + (size_t)row * 2048;
#pragma unroll
  for (int it = 0; it < 8; ++it) {
    int key = it * 256 + w * 64 + lane;
    unsigned long long bal = __ballot(mrow[key] == 1);
    if (lane == 0) pack[(size_t)row * 32 + it * 4 + w] = bal;
  }
}

// ---------------- GEMM: C[8192][N] = A[8192][1024] @ Bt[N][1024]^T ----------------
// EPI==0: scatter bf16 into Q (pre-scaled by 0.125) / K [bh][2048][64], V^T [bh][64][2048]
// EPI==1: f32 out + bias
template <int EPI>
__global__ __launch_bounds__(256) void k_gemm(
    const unsigned short* __restrict__ A, const unsigned short* __restrict__ Bt,
    unsigned short* __restrict__ Qo, unsigned short* __restrict__ Ko,
    unsigned short* __restrict__ Vo, float* __restrict__ Co,
    const float* __restrict__ bias) {
  __shared__ __align__(16) short As[128 * 64];   // 16KB, swizzled content
  __shared__ __align__(16) short Bs[128 * 64];
  const int t = threadIdx.x;
  const int bn = blockIdx.x, bm = blockIdx.y;
  const int wid = t >> 6, lane = t & 63, g = lane >> 4, l15 = lane & 15;
  const int wr = wid >> 1, wc = wid & 1;
  f32x4 zero = {0.f, 0.f, 0.f, 0.f};
  f32x4 acc[4][4];
#pragma unroll
  for (int i = 0; i < 4; ++i)
#pragma unroll
    for (int j = 0; j < 4; ++j) acc[i][j] = zero;

  const char* Ab = (const char*)(A + (size_t)bm * 128 * 1024);  // row stride 2048B
  const char* Bb = (const char*)(Bt + (size_t)bn * 128 * 1024);

  for (int k0 = 0; k0 < 2048; k0 += 128) {   // K-step: 64 elems = 128 bytes
#pragma unroll
    for (int q = 0; q < 4; ++q) {
      int idx = t + q * 256, r = idx >> 3, c = idx & 7;
      int sw = (c * 16) ^ ((r & 7) << 4);
      gload16(Ab + (size_t)r * 2048 + k0 + sw, (char*)As + idx * 16);
      gload16(Bb + (size_t)r * 2048 + k0 + sw, (char*)Bs + idx * 16);
    }
    asm volatile("s_waitcnt vmcnt(0)" ::: "memory");
    __syncthreads();
#pragma unroll
    for (int ks = 0; ks < 2; ++ks) {
      bf16x8 a[4], b[4];
#pragma unroll
      for (int mi = 0; mi < 4; ++mi) a[mi] = ldsw(As, wr * 64 + mi * 16 + l15, ks * 32 + g * 8);
#pragma unroll
      for (int ni = 0; ni < 4; ++ni) b[ni] = ldsw(Bs, wc * 64 + ni * 16 + l15, ks * 32 + g * 8);
#pragma unroll
      for (int mi = 0; mi < 4; ++mi)
#pragma unroll
        for (int ni = 0; ni < 4; ++ni)
          acc[mi][ni] = __builtin_amdgcn_mfma_f32_16x16x32_bf16(a[mi], b[ni], acc[mi][ni], 0, 0, 0);
    }
    __syncthreads();
  }

#pragma unroll
  for (int mi = 0; mi < 4; ++mi) {
#pragma unroll
    for (int ni = 0; ni < 4; ++ni) {
#pragma unroll
      for (int j = 0; j < 4; ++j) {
        float v = acc[mi][ni][j];
        int row = bm * 128 + wr * 64 + mi * 16 + g * 4 + j;  // D row map
        int col = bn * 128 + wc * 64 + ni * 16 + l15;        // D col map
        if (EPI == 0) {
          int b = row >> 11, nn = row & 2047;
          int s = col >> 10, rem = col & 1023;
          int h = rem >> 6, d = rem & 63;
          int bh = b * 16 + h;
          if (s == 0) Qo[(((size_t)bh) * 2048 + nn) * 64 + d] = f2bf(v * 0.125f);
          else if (s == 1) Ko[(((size_t)bh) * 2048 + nn) * 64 + d] = f2bf(v);
          else Vo[(((size_t)bh) * 64 + d) * 2048 + nn] = f2bf(v);   // V transposed
        } else {
          Co[(size_t)row * 1024 + col] = v + bias[col];
        }
      }
    }
  }
}

// ---------------- flash attention ----------------
// grid 2048 (XCD-swizzled), 256 threads = 4 waves x 16 q-rows; KV tile 64, dbuf
__global__ __launch_bounds__(256) void k_attn(
    const unsigned short* __restrict__ Q, const unsigned short* __restrict__ K,
    const unsigned short* __restrict__ Vt_g, const unsigned long long* __restrict__ pack,
    unsigned short* __restrict__ O) {
  __shared__ __align__(16) short Qs[64 * 64];       // 8KB
  __shared__ __align__(16) short Ks[2][64 * 64];    // 16KB
  __shared__ __align__(16) short Vt[2][64 * 64];    // 16KB  [d][key]
  __shared__ __align__(16) short Ps[4][16][72];     // 9.2KB per-wave P, padded
  const int bid0 = blockIdx.x;
  const int bid = (bid0 & 7) * 256 + (bid0 >> 3);   // XCD chunked swizzle (2048%8==0)
  const int qt = bid & 31, bh = bid >> 5;
  const int b = bh >> 4;
  const int t = threadIdx.x, wid = t >> 6, lane = t & 63, g = lane >> 4, l15 = lane & 15;
  const char* Qb = (const char*)(Q + (size_t)bh * (2048 * 64));   // row 128B
  const char* Kb = (const char*)(K + (size_t)bh * (2048 * 64));   // row 128B
  const char* Vb = (const char*)(Vt_g + (size_t)bh * (64 * 2048)); // row 4096B

  // prologue: stage Q + K/V tile 0 (swizzled source, linear LDS)
#pragma unroll
  for (int q = 0; q < 2; ++q) {
    int idx = t + q * 256, r = idx >> 3, c = idx & 7;
    int sw = (c * 16) ^ ((r & 7) << 4);
    gload16(Qb + (size_t)(qt * 64 + r) * 128 + sw, (char*)Qs + idx * 16);
    gload16(Kb + (size_t)r * 128 + sw, (char*)Ks[0] + idx * 16);
    gload16(Vb + (size_t)r * 4096 + sw, (char*)Vt[0] + idx * 16);
  }
  asm volatile("s_waitcnt vmcnt(0)" ::: "memory");
  __syncthreads();

  f32x4 zero = {0.f, 0.f, 0.f, 0.f};
  f32x4 oacc[4];
#pragma unroll
  for (int nf = 0; nf < 4; ++nf) oacc[nf] = zero;
  float lpart[4] = {0.f, 0.f, 0.f, 0.f};
  const int qrow0 = qt * 64 + wid * 16 + g * 4;
  const unsigned long long* mrow = pack + ((size_t)b * 2048 + qrow0) * 32;

  int cb = 0;
  for (int kt = 0; kt < 32; ++kt) {
    const int nb = cb ^ 1;
    // mask words first (so their waitcnt doesn't drain the stage queue)
    unsigned long long mw0 = mrow[0 * 32 + kt];
    unsigned long long mw1 = mrow[1 * 32 + kt];
    unsigned long long mw2 = mrow[2 * 32 + kt];
    unsigned long long mw3 = mrow[3 * 32 + kt];
    // issue next tile's stage (lands under this tile's compute)
    if (kt + 1 < 32) {
#pragma unroll
      for (int q = 0; q < 2; ++q) {
        int idx = t + q * 256, r = idx >> 3, c = idx & 7;
        int sw = (c * 16) ^ ((r & 7) << 4);
        gload16(Kb + (size_t)((kt + 1) * 64 + r) * 128 + sw, (char*)Ks[nb] + idx * 16);
        gload16(Vb + (size_t)r * 4096 + (kt + 1) * 128 + sw, (char*)Vt[nb] + idx * 16);
      }
    }

    // S = Q @ K^T  (scores pre-scaled by 0.125 via Q)
    f32x4 sf[4];
#pragma unroll
    for (int nf = 0; nf < 4; ++nf) sf[nf] = zero;
    __builtin_amdgcn_s_setprio(1);
#pragma unroll
    for (int ks = 0; ks < 2; ++ks) {
      bf16x8 aq = ldsw(Qs, wid * 16 + l15, ks * 32 + g * 8);
#pragma unroll
      for (int nf = 0; nf < 4; ++nf) {
        bf16x8 bk = ldsw(Ks[cb], nf * 16 + l15, ks * 32 + g * 8);
        sf[nf] = __builtin_amdgcn_mfma_f32_16x16x32_bf16(aq, bk, sf[nf], 0, 0, 0);
      }
    }
    __builtin_amdgcn_s_setprio(0);

    // no-max softmax: P = exp(s), masked -> 0; lane-local partial row sums
#pragma unroll
    for (int j = 0; j < 4; ++j) {
      unsigned long long mw = (j == 0) ? mw0 : (j == 1) ? mw1 : (j == 2) ? mw2 : mw3;
      unsigned alo = (unsigned)mw >> l15;
      unsigned ahi = (unsigned)(mw >> 32) >> l15;
      float e0 = __expf(sf[0][j]); if (alo & 1u)       e0 = 0.f;
      float e1 = __expf(sf[1][j]); if (alo & 0x10000u) e1 = 0.f;
      float e2 = __expf(sf[2][j]); if (ahi & 1u)       e2 = 0.f;
      float e3 = __expf(sf[3][j]); if (ahi & 0x10000u) e3 = 0.f;
      lpart[j] += (e0 + e1) + (e2 + e3);
      // truncating f32->bf16 (P >= 0, rel err <= 2^-8)
      Ps[wid][g * 4 + j][0 * 16 + l15] = (short)(__builtin_bit_cast(unsigned, e0) >> 16);
      Ps[wid][g * 4 + j][1 * 16 + l15] = (short)(__builtin_bit_cast(unsigned, e1) >> 16);
      Ps[wid][g * 4 + j][2 * 16 + l15] = (short)(__builtin_bit_cast(unsigned, e2) >> 16);
      Ps[wid][g * 4 + j][3 * 16 + l15] = (short)(__builtin_bit_cast(unsigned, e3) >> 16);
    }
    // within-wave Ps write->read ordering
    asm volatile("s_waitcnt lgkmcnt(0)" ::: "memory");
    __builtin_amdgcn_sched_barrier(0);

    // O += P @ V
    __builtin_amdgcn_s_setprio(1);
#pragma unroll
    for (int ks = 0; ks < 2; ++ks) {
      bf16x8 ap = *reinterpret_cast<const bf16x8*>(&Ps[wid][l15][ks * 32 + g * 8]);
#pragma unroll
      for (int nf = 0; nf < 4; ++nf) {
        bf16x8 bv = ldsw(Vt[cb], nf * 16 + l15, ks * 32 + g * 8);
        oacc[nf] = __builtin_amdgcn_mfma_f32_16x16x32_bf16(ap, bv, oacc[nf], 0, 0, 0);
      }
    }
    __builtin_amdgcn_s_setprio(0);

    asm volatile("s_waitcnt vmcnt(0)" ::: "memory");  // next tile staged
    __syncthreads();
    cb = nb;
  }

  // final row-sum reduce (16 lanes per row) + output write
  const int h = bh & 15;
#pragma unroll
  for (int j = 0; j < 4; ++j) {
    float l = lpart[j];
    l += __shfl_xor(l, 1);
    l += __shfl_xor(l, 2);
    l += __shfl_xor(l, 4);
    l += __shfl_xor(l, 8);
    float inv = 1.0f / l;
    int qg = qrow0 + j;
#pragma unroll
    for (int nf = 0; nf < 4; ++nf) {
      int d = nf * 16 + l15;
      O[((size_t)b * 2048 + qg) * 1024 + h * 64 + d] = f2bf(oacc[nf][j] * inv);
    }
  }
}

extern "C" void kernel_launch(void* const* d_in, const int* in_sizes, int n_in,
                              void* d_out, int out_size, void* d_ws, size_t ws_size,
                              hipStream_t stream) {
  (void)in_sizes; (void)n_in; (void)out_size; (void)ws_size;
  const float* x = (const float*)d_in[0];
  const int* mask = (const int*)d_in[1];
  const float* Wqkv = (const float*)d_in[2];
  const float* Wout = (const float*)d_in[3];
  const float* bout = (const float*)d_in[4];
  float* out = (float*)d_out;

  unsigned short* ws = (unsigned short*)d_ws;
  unsigned short* Xb   = ws;                  // 8,388,608 elems
  unsigned short* Wq_t = Xb + 8388608;        // 3,145,728
  unsigned short* Wo_t = Wq_t + 3145728;      // 1,048,576
  unsigned short* Qa   = Wo_t + 1048576;      // 8,388,608 (pre-scaled by 0.125)
  unsigned short* Ka   = Qa + 8388608;        // 8,388,608
  unsigned short* Va   = Ka + 8388608;        // 8,388,608 (transposed [bh][64][2048])
  unsigned short* ATT  = Va + 8388608;        // 8,388,608
  unsigned long long* MP = (unsigned long long*)(ATT + 8388608);  // 2 MB

  k_cvt<<<8192, 256, 0, stream>>>(x, Xb);
  k_transpose_cvt<<<dim3(96, 32), 256, 0, stream>>>(Wqkv, Wq_t, 1024, 3072);
  k_transpose_cvt<<<dim3(32, 32), 256, 0, stream>>>(Wout, Wo_t, 1024, 1024);
  k_packmask<<<8192, 256, 0, stream>>>(mask, MP);
  k_gemm<0><<<dim3(24, 64), 256, 0, stream>>>(Xb, Wq_t, Qa, Ka, Va, nullptr, nullptr);
  k_attn<<<2048, 256, 0, stream>>>(Qa, Ka, Va, MP, ATT);
  k_gemm<1><<<dim3(8, 64), 256, 0, stream>>>(ATT, Wo_t, nullptr, nullptr, nullptr, out, bout);
}

// Round 4
// 256.261 us; speedup vs baseline: 1.7192x; 1.1621x over previous
//
#include <hip/hip_runtime.h>
#include <hip/hip_bf16.h>

// SelfAttentionMasked: B=4, N=2048, DIM=1024, H=16, DH=64
// cvt(x) -> transpose_cvt(W) -> packmask -> QKV GEMM (gload_lds+swizzle, Q pre-scaled
// by 0.125*log2e) -> flash attn (swapped QK^T, lane-local softmax, exp2, bitmask,
// dbuf gload_lds, 8 waves) -> out GEMM + bias

typedef __attribute__((ext_vector_type(8))) short bf16x8;
typedef __attribute__((ext_vector_type(4))) float f32x4;

__device__ __forceinline__ unsigned short f2bf(float f) {
  unsigned u = __builtin_bit_cast(unsigned, f);
  u += 0x7fffu + ((u >> 16) & 1u);   // RNE
  return (unsigned short)(u >> 16);
}

// async global->LDS, 16B per lane; LDS dest linear (wave-uniform base + lane*16)
__device__ __forceinline__ void gload16(const void* g, void* l) {
  __builtin_amdgcn_global_load_lds(
      (const __attribute__((address_space(1))) unsigned int*)g,
      (__attribute__((address_space(3))) unsigned int*)l, 16, 0, 0);
}

// swizzled b128 read from a [rows][64-elem] linear LDS tile staged with
// source-byte ^= ((row&7)<<4). elem must be a multiple of 8.
__device__ __forceinline__ bf16x8 ldsw(const short* base, int row, int elem) {
  const char* p = (const char*)base + row * 128 + ((elem * 2) ^ ((row & 7) << 4));
  return *(const bf16x8*)p;
}

// ---------------- convert f32 -> bf16 flat ----------------
__global__ __launch_bounds__(256) void k_cvt(const float* __restrict__ in,
                                             unsigned short* __restrict__ out) {
  int i = (blockIdx.x * 256 + threadIdx.x) * 4;
  float4 v = *reinterpret_cast<const float4*>(in + i);
  ushort4 o;
  o.x = f2bf(v.x); o.y = f2bf(v.y); o.z = f2bf(v.z); o.w = f2bf(v.w);
  *reinterpret_cast<ushort4*>(out + i) = o;
}

// ------- transpose + convert: in [rows][cols] f32 -> out [cols][rows] bf16 -------
__global__ __launch_bounds__(256) void k_transpose_cvt(const float* __restrict__ in,
                                                       unsigned short* __restrict__ out,
                                                       int rows, int cols) {
  __shared__ float tile[32][33];
  int tx = threadIdx.x & 31, ty = threadIdx.x >> 5;  // 32 x 8
  int c0 = blockIdx.x * 32, r0 = blockIdx.y * 32;
#pragma unroll
  for (int i = 0; i < 32; i += 8)
    tile[ty + i][tx] = in[(size_t)(r0 + ty + i) * cols + (c0 + tx)];
  __syncthreads();
#pragma unroll
  for (int i = 0; i < 32; i += 8)
    out[(size_t)(c0 + ty + i) * rows + (r0 + tx)] = f2bf(tile[tx][ty + i]);
}

// ------- pack mask int32 [row][2048] -> bits uint64 [row][32] (bit k = masked) ----
__global__ __launch_bounds__(256) void k_packmask(const int* __restrict__ mask,
                                                  unsigned long long* __restrict__ pack) {
  const int row = blockIdx.x;              // b*2048 + n
  const int t = threadIdx.x, w = t >> 6, lane = t & 63;
  const int* mrow = mask + (size_t)row * 2048;
#pragma unroll
  for (int it = 0; it < 8; ++it) {
    int key = it * 256 + w * 64 + lane;
    unsigned long long bal = __ballot(mrow[key] == 1);
    if (lane == 0) pack[(size_t)row * 32 + it * 4 + w] = bal;
  }
}

// ---------------- GEMM: C[8192][N] = A[8192][1024] @ Bt[N][1024]^T ----------------
// EPI==0: scatter bf16 into Q (pre-scaled by 0.125*log2e) / K [bh][2048][64],
//         V^T [bh][64][2048]
// EPI==1: f32 out + bias
template <int EPI>
__global__ __launch_bounds__(256) void k_gemm(
    const unsigned short* __restrict__ A, const unsigned short* __restrict__ Bt,
    unsigned short* __restrict__ Qo, unsigned short* __restrict__ Ko,
    unsigned short* __restrict__ Vo, float* __restrict__ Co,
    const float* __restrict__ bias) {
  __shared__ __align__(16) short As[128 * 64];   // 16KB, swizzled content
  __shared__ __align__(16) short Bs[128 * 64];
  const int t = threadIdx.x;
  const int bn = blockIdx.x, bm = blockIdx.y;
  const int wid = t >> 6, lane = t & 63, g = lane >> 4, l15 = lane & 15;
  const int wr = wid >> 1, wc = wid & 1;
  f32x4 zero = {0.f, 0.f, 0.f, 0.f};
  f32x4 acc[4][4];
#pragma unroll
  for (int i = 0; i < 4; ++i)
#pragma unroll
    for (int j = 0; j < 4; ++j) acc[i][j] = zero;

  const char* Ab = (const char*)(A + (size_t)bm * 128 * 1024);  // row stride 2048B
  const char* Bb = (const char*)(Bt + (size_t)bn * 128 * 1024);

  for (int k0 = 0; k0 < 2048; k0 += 128) {   // K-step: 64 elems = 128 bytes
#pragma unroll
    for (int q = 0; q < 4; ++q) {
      int idx = t + q * 256, r = idx >> 3, c = idx & 7;
      int sw = (c * 16) ^ ((r & 7) << 4);
      gload16(Ab + (size_t)r * 2048 + k0 + sw, (char*)As + idx * 16);
      gload16(Bb + (size_t)r * 2048 + k0 + sw, (char*)Bs + idx * 16);
    }
    asm volatile("s_waitcnt vmcnt(0)" ::: "memory");
    __syncthreads();
#pragma unroll
    for (int ks = 0; ks < 2; ++ks) {
      bf16x8 a[4], b[4];
#pragma unroll
      for (int mi = 0; mi < 4; ++mi) a[mi] = ldsw(As, wr * 64 + mi * 16 + l15, ks * 32 + g * 8);
#pragma unroll
      for (int ni = 0; ni < 4; ++ni) b[ni] = ldsw(Bs, wc * 64 + ni * 16 + l15, ks * 32 + g * 8);
#pragma unroll
      for (int mi = 0; mi < 4; ++mi)
#pragma unroll
        for (int ni = 0; ni < 4; ++ni)
          acc[mi][ni] = __builtin_amdgcn_mfma_f32_16x16x32_bf16(a[mi], b[ni], acc[mi][ni], 0, 0, 0);
    }
    __syncthreads();
  }

#pragma unroll
  for (int mi = 0; mi < 4; ++mi) {
#pragma unroll
    for (int ni = 0; ni < 4; ++ni) {
#pragma unroll
      for (int j = 0; j < 4; ++j) {
        float v = acc[mi][ni][j];
        int row = bm * 128 + wr * 64 + mi * 16 + g * 4 + j;  // D row map
        int col = bn * 128 + wc * 64 + ni * 16 + l15;        // D col map
        if (EPI == 0) {
          int b = row >> 11, nn = row & 2047;
          int s = col >> 10, rem = col & 1023;
          int h = rem >> 6, d = rem & 63;
          int bh = b * 16 + h;
          // 0.125 * log2(e) = 0.18033688...; softmax then uses exp2 directly
          if (s == 0) Qo[(((size_t)bh) * 2048 + nn) * 64 + d] = f2bf(v * 0.18033688011112042f);
          else if (s == 1) Ko[(((size_t)bh) * 2048 + nn) * 64 + d] = f2bf(v);
          else Vo[(((size_t)bh) * 64 + d) * 2048 + nn] = f2bf(v);   // V transposed
        } else {
          Co[(size_t)row * 1024 + col] = v + bias[col];
        }
      }
    }
  }
}

// ---------------- flash attention ----------------
// grid 1024 (XCD-swizzled), 512 threads = 8 waves x 16 q-rows (QBLK=128); KV tile 64
// Swapped QK^T: S^T = mfma(K, Q) -> lane (g,l15) holds keys {nf*16+g*4+j} for q=l15.
__global__ __launch_bounds__(512, 5) void k_attn(
    const unsigned short* __restrict__ Q, const unsigned short* __restrict__ K,
    const unsigned short* __restrict__ Vt_g, const unsigned long long* __restrict__ pack,
    unsigned short* __restrict__ O) {
  __shared__ __align__(16) short Ks[2][64 * 64];    // 16KB
  __shared__ __align__(16) short Vt[2][64 * 64];    // 16KB  [d][key]
  __shared__ __align__(16) short Ps[8][16 * 72];    // 18KB per-wave P [q][key], pad 72
  const int bid0 = blockIdx.x;
  const int bid = (bid0 & 7) * 128 + (bid0 >> 3);   // XCD chunked swizzle (1024%8==0)
  const int qt = bid & 15, bh = bid >> 4;           // 16 q-tiles of 128
  const int b = bh >> 4;
  const int t = threadIdx.x, wid = t >> 6, lane = t & 63, g = lane >> 4, l15 = lane & 15;
  const char* Kb = (const char*)(K + (size_t)bh * (2048 * 64));     // row 128B
  const char* Vb = (const char*)(Vt_g + (size_t)bh * (64 * 2048));  // row 4096B
  const unsigned short* Qb = Q + (size_t)bh * (2048 * 64);

  // prologue: stage K/V tile 0 (swizzled source, linear LDS); 1 gload each per thread
  {
    int r = t >> 3, c = t & 7;
    int sw = (c * 16) ^ ((r & 7) << 4);
    gload16(Kb + (size_t)r * 128 + sw, (char*)Ks[0] + t * 16);
    gload16(Vb + (size_t)r * 4096 + sw, (char*)Vt[0] + t * 16);
  }
  // Q fragments to registers (B-operand of swapped QK^T): q = l15 row of wave's block
  const int qrow = qt * 128 + wid * 16 + l15;
  bf16x8 qf0 = *reinterpret_cast<const bf16x8*>(Qb + (size_t)qrow * 64 + g * 8);
  bf16x8 qf1 = *reinterpret_cast<const bf16x8*>(Qb + (size_t)qrow * 64 + 32 + g * 8);
  asm volatile("s_waitcnt vmcnt(0)" ::: "memory");
  __syncthreads();

  f32x4 zero = {0.f, 0.f, 0.f, 0.f};
  f32x4 oacc[4];
#pragma unroll
  for (int nf = 0; nf < 4; ++nf) oacc[nf] = zero;
  float lp = 0.f;                                   // partial row-sum for q=l15
  const unsigned long long* mrow = pack + ((size_t)b * 2048 + qrow) * 32;
  short* Pw = &Ps[wid][0];                          // [16 q][72]

  int cb = 0;
  for (int kt = 0; kt < 32; ++kt) {
    unsigned long long mw = mrow[kt];               // issued before stage (stays oldest)
    if (kt + 1 < 32) {                              // prefetch next K/V tile
      int r = t >> 3, c = t & 7;
      int sw = (c * 16) ^ ((r & 7) << 4);
      gload16(Kb + (size_t)((kt + 1) * 64 + r) * 128 + sw, (char*)Ks[cb ^ 1] + t * 16);
      gload16(Vb + (size_t)r * 4096 + (kt + 1) * 128 + sw, (char*)Vt[cb ^ 1] + t * 16);
    }

    // S^T = K @ Q^T : lane reg j of frag nf = S[key=nf*16+g*4+j][q=l15]
    f32x4 sf[4];
#pragma unroll
    for (int nf = 0; nf < 4; ++nf) sf[nf] = zero;
    __builtin_amdgcn_s_setprio(1);
#pragma unroll
    for (int ks = 0; ks < 2; ++ks) {
      bf16x8 qk = ks ? qf1 : qf0;
#pragma unroll
      for (int nf = 0; nf < 4; ++nf) {
        bf16x8 kk = ldsw(Ks[cb], nf * 16 + l15, ks * 32 + g * 8);
        sf[nf] = __builtin_amdgcn_mfma_f32_16x16x32_bf16(kk, qk, sf[nf], 0, 0, 0);
      }
    }
    __builtin_amdgcn_s_setprio(0);

    // lane-local softmax (no-max): mask bits, exp2, accumulate sum, pack, write P
    unsigned mlo = (unsigned)mw >> (g * 4);         // keys nf*16+g*4+j, nf<2 -> bit nf*16+j
    unsigned mhi = (unsigned)(mw >> 32) >> (g * 4); // nf>=2 -> bit (nf-2)*16+j
#pragma unroll
    for (int nf = 0; nf < 4; ++nf) {
      unsigned msrc = (nf < 2) ? mlo : mhi;
      unsigned eu[4];
#pragma unroll
      for (int j = 0; j < 4; ++j) {
        float s = sf[nf][j];
        if (msrc & (1u << ((nf & 1) * 16 + j))) s = -1e30f;
        float e = __builtin_amdgcn_exp2f(s);        // scores pre-scaled by 0.125*log2e
        lp += e;
        eu[j] = __builtin_bit_cast(unsigned, e);
      }
      // pack 4 trunc-bf16 into 2 dwords, one b64 write (keys nf*16+g*4 .. +3)
      uint2 pk;
      pk.x = __builtin_amdgcn_perm(eu[1], eu[0], 0x07060302);
      pk.y = __builtin_amdgcn_perm(eu[3], eu[2], 0x07060302);
      *reinterpret_cast<uint2*>(&Pw[l15 * 72 + nf * 16 + g * 4]) = pk;
    }
    // within-wave Ps write->read ordering
    asm volatile("s_waitcnt lgkmcnt(0)" ::: "memory");
    __builtin_amdgcn_sched_barrier(0);

    // O += P @ V : A-frag = P[q=l15][ks*32+g*8..+7] (b128), B-frag = Vt rows
    __builtin_amdgcn_s_setprio(1);
#pragma unroll
    for (int ks = 0; ks < 2; ++ks) {
      bf16x8 ap = *reinterpret_cast<const bf16x8*>(&Pw[l15 * 72 + ks * 32 + g * 8]);
#pragma unroll
      for (int nf = 0; nf < 4; ++nf) {
        bf16x8 bv = ldsw(Vt[cb], nf * 16 + l15, ks * 32 + g * 8);
        oacc[nf] = __builtin_amdgcn_mfma_f32_16x16x32_bf16(ap, bv, oacc[nf], 0, 0, 0);
      }
    }
    __builtin_amdgcn_s_setprio(0);

    asm volatile("s_waitcnt vmcnt(0)" ::: "memory");  // next tile staged
    __syncthreads();
    cb ^= 1;
  }

  // total row-sum for q=l15 (4 lanes per q across g-groups), redistribute inverse
  float l = lp;
  l += __shfl_xor(l, 16);
  l += __shfl_xor(l, 32);
  float invl = 1.0f / l;
  float inv[4];
#pragma unroll
  for (int j = 0; j < 4; ++j) inv[j] = __shfl(invl, g * 4 + j);  // lane l15==g*4+j

  // write attention output: ATT[b][n][h*64+d] bf16 ; O-tile: q=g*4+j, d=nf*16+l15
  const int h = bh & 15;
#pragma unroll
  for (int nf = 0; nf < 4; ++nf) {
#pragma unroll
    for (int j = 0; j < 4; ++j) {
      int qg = qt * 128 + wid * 16 + g * 4 + j;
      int d = nf * 16 + l15;
      O[((size_t)b * 2048 + qg) * 1024 + h * 64 + d] = f2bf(oacc[nf][j] * inv[j]);
    }
  }
}

extern "C" void kernel_launch(void* const* d_in, const int* in_sizes, int n_in,
                              void* d_out, int out_size, void* d_ws, size_t ws_size,
                              hipStream_t stream) {
  (void)in_sizes; (void)n_in; (void)out_size; (void)ws_size;
  const float* x = (const float*)d_in[0];
  const int* mask = (const int*)d_in[1];
  const float* Wqkv = (const float*)d_in[2];
  const float* Wout = (const float*)d_in[3];
  const float* bout = (const float*)d_in[4];
  float* out = (float*)d_out;

  unsigned short* ws = (unsigned short*)d_ws;
  unsigned short* Xb   = ws;                  // 8,388,608 elems
  unsigned short* Wq_t = Xb + 8388608;        // 3,145,728
  unsigned short* Wo_t = Wq_t + 3145728;      // 1,048,576
  unsigned short* Qa   = Wo_t + 1048576;      // 8,388,608 (pre-scaled by 0.125*log2e)
  unsigned short* Ka   = Qa + 8388608;        // 8,388,608
  unsigned short* Va   = Ka + 8388608;        // 8,388,608 (transposed [bh][64][2048])
  unsigned short* ATT  = Va + 8388608;        // 8,388,608
  unsigned long long* MP = (unsigned long long*)(ATT + 8388608);  // 2 MB

  k_cvt<<<8192, 256, 0, stream>>>(x, Xb);
  k_transpose_cvt<<<dim3(96, 32), 256, 0, stream>>>(Wqkv, Wq_t, 1024, 3072);
  k_transpose_cvt<<<dim3(32, 32), 256, 0, stream>>>(Wout, Wo_t, 1024, 1024);
  k_packmask<<<8192, 256, 0, stream>>>(mask, MP);
  k_gemm<0><<<dim3(24, 64), 256, 0, stream>>>(Xb, Wq_t, Qa, Ka, Va, nullptr, nullptr);
  k_attn<<<1024, 512, 0, stream>>>(Qa, Ka, Va, MP, ATT);
  k_gemm<1><<<dim3(8, 64), 256, 0, stream>>>(ATT, Wo_t, nullptr, nullptr, nullptr, out, bout);
}